// Round 6
// baseline (438.020 us; speedup 1.0000x reference)
//
#include <hip/hip_runtime.h>

typedef unsigned int uint;
typedef unsigned long long u64;

#define TD 20000
// ws layout in float units:
//  H:   [200][12][4] = 9600 floats (FIR taps {e_s,i_s,e_ns,i_ns} per (k,s))
//  ME:  4 arrays x 512 u64  (E spread masks, element 4g+j -> array j idx g; pad 0)
//  MI:  4 arrays x 128 u64  (I spread masks, same split; pad 0)
//  IN:  [20000][24]  (e counts 0..11, i counts 12..23)
//  SYN: [20000][24]  (syn_s 0..11, syn_ns 12..23)
#define WS_H   0
#define WS_ME  9600
#define WS_MI  13696
#define WS_IN  14720
#define WS_SYN 494720

__device__ __forceinline__ float sigf(float x) { return 1.f / (1.f + __expf(-x)); }

// ---------------- K1: FIR kernels + split spread connectivity masks ----------------
__global__ __launch_bounds__(256) void k1_precomp(
    const float* __restrict__ Ce, const float* __restrict__ Ci,
    const float* __restrict__ Wsy_s, const float* __restrict__ Wsy_ns,
    const float* __restrict__ Del_s, const float* __restrict__ Del_ns,
    float* __restrict__ ws) {
  int p = blockIdx.x * 256 + threadIdx.x;
  if (p < 2400) {
    int k = p / 12, s = p - (p / 12) * 12;
    float o[4];
    for (int ch = 0; ch < 2; ++ch) {
      const float* W = ch ? Wsy_ns : Wsy_s;
      const float* D = ch ? Del_ns : Del_s;
      for (int c = 0; c < 2; ++c) {
        float ts = fmaxf((float)k - __expf(D[s * 2 + c]), 0.f);
        float v = 0.f;
        for (int b = 0; b < 3; ++b) {
          float tt = ts * __expf(-0.5f * (float)b);
          v += W[s * 6 + b * 2 + c] * tt * __expf(-tt);
        }
        o[ch * 2 + c] = v;
      }
    }
    float* H = ws + WS_H + (size_t)(k * 12 + s) * 4;
    H[0] = o[0]; H[1] = o[1]; H[2] = o[2]; H[3] = o[3];
  }
  int q = p - 2400;
  if (q >= 0 && q < 2500) {
    uint m = 0;
    if (q < 2000) {
      for (int s = 0; s < 12; ++s) m |= (Ce[s * 2000 + q] != 0.f ? (1u << s) : 0u);
    } else {
      int e = q - 2000;
      for (int s = 0; s < 12; ++s) m |= (Ci[s * 500 + e] != 0.f ? (1u << s) : 0u);
    }
    u64 sp = 0ull;
    for (int s = 0; s < 12; ++s) sp |= (u64)((m >> s) & 1u) << (5 * s);
    uint2 v = make_uint2((uint)sp, (uint)(sp >> 32));
    if (q < 2000) {
      int g = q >> 2, j = q & 3;
      ((uint2*)(ws + WS_ME))[j * 512 + g] = v;
    } else {
      int e = q - 2000;
      int g = e >> 2, j = e & 3;
      ((uint2*)(ws + WS_MI))[j * 128 + g] = v;
    }
  }
  // zero pads: E groups 500..511 (x4 arrays), I groups 125..127 (x4 arrays)
  int z = p - 4900;
  if (z >= 0 && z < 48) {
    int j = z / 12, g = 500 + z % 12;
    ((uint2*)(ws + WS_ME))[j * 512 + g] = make_uint2(0u, 0u);
  }
  int zi = p - 4948;
  if (zi >= 0 && zi < 12) {
    int j = zi / 3, g = 125 + zi % 3;
    ((uint2*)(ws + WS_MI))[j * 128 + g] = make_uint2(0u, 0u);
  }
}

// ---------------- K2: IN = S @ C^T via spread-mask accumulation ----------------
// v5: persistent blocks (2048 = 8/CU, all co-resident; masks preloaded once,
// waves grid-stride over rows). Masks in 4 split u64 arrays -> ds_read_b64 at
// 8 B/lane stride = 2-way alias = free. All 10 global loads issue up-front per
// row. Integer-exact (5-bit fields, flush every 4 float4s).
__global__ __launch_bounds__(256, 8) void k2_project(
    const float* __restrict__ Se, const float* __restrict__ Si,
    float* __restrict__ ws) {
  __shared__ __align__(16) uint2 sp[2560];  // E: j*512+g (0..2047), I: 2048+j*128+g
  {
    const uint2* g = (const uint2*)(ws + WS_ME);
    for (int p = threadIdx.x; p < 2560; p += 256) sp[p] = g[p];
  }
  __syncthreads();
  const int lane = threadIdx.x & 63;
  const int wv = blockIdx.x * 4 + (threadIdx.x >> 6);  // 8192 waves
  float* INb = ws + WS_IN;
  const float4 z4 = make_float4(0.f, 0.f, 0.f, 0.f);

  for (int t = wv; t < TD; t += 8192) {
    const float4* Sr = (const float4*)(Se + (size_t)t * 2000);
    const float4* Sir = (const float4*)(Si + (size_t)t * 500);
    // ---- issue ALL global loads first ----
    float4 sv[8];
#pragma unroll
    for (int it = 0; it < 7; ++it) sv[it] = Sr[lane + it * 64];
    sv[7] = (lane < 52) ? Sr[448 + lane] : z4;       // i4 in [448,500)
    float4 si0 = Sir[lane];                          // i4 in [0,64)
    float4 si1 = (lane < 61) ? Sir[64 + lane] : z4;  // i4 in [64,125)

    // ---- E channel ----
    uint eTot[12];
#pragma unroll
    for (int s = 0; s < 12; ++s) eTot[s] = 0u;
    u64 acc = 0ull;
#pragma unroll
    for (int it = 0; it < 8; ++it) {
      int i4 = lane + it * 64;  // <= 511, pads are zero
      uint2 a0 = sp[i4];
      uint2 a1 = sp[512 + i4];
      uint2 a2 = sp[1024 + i4];
      uint2 a3 = sp[1536 + i4];
      acc += (sv[it].x != 0.f ? ((u64)a0.x | ((u64)a0.y << 32)) : 0ull);
      acc += (sv[it].y != 0.f ? ((u64)a1.x | ((u64)a1.y << 32)) : 0ull);
      acc += (sv[it].z != 0.f ? ((u64)a2.x | ((u64)a2.y << 32)) : 0ull);
      acc += (sv[it].w != 0.f ? ((u64)a3.x | ((u64)a3.y << 32)) : 0ull);
      if (it == 3) {
#pragma unroll
        for (int s = 0; s < 12; ++s) eTot[s] += (uint)(acc >> (5 * s)) & 31u;
        acc = 0ull;
      }
    }
#pragma unroll
    for (int s = 0; s < 12; ++s) eTot[s] += (uint)(acc >> (5 * s)) & 31u;

    // ---- I channel (max 8 adds/field, no flush) ----
    u64 accI = 0ull;
    {
      int i4 = lane;
      uint2 a0 = sp[2048 + i4];
      uint2 a1 = sp[2176 + i4];
      uint2 a2 = sp[2304 + i4];
      uint2 a3 = sp[2432 + i4];
      accI += (si0.x != 0.f ? ((u64)a0.x | ((u64)a0.y << 32)) : 0ull);
      accI += (si0.y != 0.f ? ((u64)a1.x | ((u64)a1.y << 32)) : 0ull);
      accI += (si0.z != 0.f ? ((u64)a2.x | ((u64)a2.y << 32)) : 0ull);
      accI += (si0.w != 0.f ? ((u64)a3.x | ((u64)a3.y << 32)) : 0ull);
      i4 = 64 + lane;  // <= 127, pads zero
      uint2 b0 = sp[2048 + i4];
      uint2 b1 = sp[2176 + i4];
      uint2 b2 = sp[2304 + i4];
      uint2 b3 = sp[2432 + i4];
      accI += (si1.x != 0.f ? ((u64)b0.x | ((u64)b0.y << 32)) : 0ull);
      accI += (si1.y != 0.f ? ((u64)b1.x | ((u64)b1.y << 32)) : 0ull);
      accI += (si1.z != 0.f ? ((u64)b2.x | ((u64)b2.y << 32)) : 0ull);
      accI += (si1.w != 0.f ? ((u64)b3.x | ((u64)b3.y << 32)) : 0ull);
    }

    uint pk[12];
#pragma unroll
    for (int s = 0; s < 12; ++s)
      pk[s] = eTot[s] | (((uint)(accI >> (5 * s)) & 31u) << 16);
#pragma unroll
    for (int s = 0; s < 12; ++s) {
      uint v = pk[s];
      v += __shfl_xor(v, 32, 64);
      v += __shfl_xor(v, 16, 64);
      v += __shfl_xor(v, 8, 64);
      v += __shfl_xor(v, 4, 64);
      v += __shfl_xor(v, 2, 64);
      v += __shfl_xor(v, 1, 64);
      pk[s] = v;
    }
    if (lane == 0) {
      float4* o = (float4*)(INb + (size_t)t * 24);
      o[0] = make_float4((float)(pk[0] & 0xffffu), (float)(pk[1] & 0xffffu),
                         (float)(pk[2] & 0xffffu), (float)(pk[3] & 0xffffu));
      o[1] = make_float4((float)(pk[4] & 0xffffu), (float)(pk[5] & 0xffffu),
                         (float)(pk[6] & 0xffffu), (float)(pk[7] & 0xffffu));
      o[2] = make_float4((float)(pk[8] & 0xffffu), (float)(pk[9] & 0xffffu),
                         (float)(pk[10] & 0xffffu), (float)(pk[11] & 0xffffu));
      o[3] = make_float4((float)(pk[0] >> 16), (float)(pk[1] >> 16),
                         (float)(pk[2] >> 16), (float)(pk[3] >> 16));
      o[4] = make_float4((float)(pk[4] >> 16), (float)(pk[5] >> 16),
                         (float)(pk[6] >> 16), (float)(pk[7] >> 16));
      o[5] = make_float4((float)(pk[8] >> 16), (float)(pk[9] >> 16),
                         (float)(pk[10] >> 16), (float)(pk[11] >> 16));
    }
  }
}

// ---------------- K3: causal FIR, K=200, s-group split across blockIdx.y ----------------
__global__ __launch_bounds__(256) void k3_conv(float* __restrict__ ws) {
  __shared__ float tile[6 * 264];
  __shared__ float red[4 * 64 * 7];
  const int g = blockIdx.y;        // subunit group: s in [3g, 3g+3)
  const int t0 = blockIdx.x * 64;
  const float* INb = ws + WS_IN;
  for (int p = threadIdx.x; p < 263 * 6; p += 256) {
    int row = p / 6, c = p - row * 6;
    int ch = (c < 3) ? (3 * g + c) : (9 + 3 * g + c);
    int gt = t0 - 199 + row;
    tile[c * 264 + row] = (gt >= 0 && gt < TD) ? INb[(size_t)gt * 24 + ch] : 0.f;
  }
  __syncthreads();
  const int lane = threadIdx.x & 63;
  const int q = threadIdx.x >> 6;
  const float4* H4 = (const float4*)(ws + WS_H);
  float accs[3] = {0.f, 0.f, 0.f}, accn[3] = {0.f, 0.f, 0.f};
  for (int kk = 0; kk < 25; ++kk) {
    int k = q * 50 + kk * 2;
    int rb = lane + 198 - k;
#pragma unroll
    for (int s = 0; s < 3; ++s) {
      float ve0 = tile[s * 264 + rb];
      float ve1 = tile[s * 264 + rb + 1];
      float vi0 = tile[(3 + s) * 264 + rb];
      float vi1 = tile[(3 + s) * 264 + rb + 1];
      float4 h0 = H4[k * 12 + 3 * g + s];
      float4 h1 = H4[(k + 1) * 12 + 3 * g + s];
      accs[s] += h0.x * ve1 + h0.y * vi1 + h1.x * ve0 + h1.y * vi0;
      accn[s] += h0.z * ve1 + h0.w * vi1 + h1.z * ve0 + h1.w * vi0;
    }
  }
  float* mr = red + (q * 64 + lane) * 7;
#pragma unroll
  for (int s = 0; s < 3; ++s) { mr[s] = accs[s]; mr[3 + s] = accn[s]; }
  __syncthreads();
  for (int p = threadIdx.x; p < 64 * 6; p += 256) {
    int row = p / 6, c = p - row * 6;
    if (t0 + row < TD) {
      float sum = red[row * 7 + c] + red[(64 + row) * 7 + c] +
                  red[(128 + row) * 7 + c] + red[(192 + row) * 7 + c];
      int ch = (c < 3) ? (3 * g + c) : (9 + 3 * g + c);
      ws[WS_SYN + (size_t)(t0 + row) * 24 + ch] = sum;
    }
  }
}

// ---------------- K45: one thread per t; nilpotent C_den => 13-step warm-up
// makes A[t-1], A[t] exact; s-chain closed-form given A[t-1]. ----------------
__global__ void k45_out(
    const float* __restrict__ Cden, const float* __restrict__ Ws_sub,
    const float* __restrict__ Wns_sub, const float* __restrict__ Th_s,
    const float* __restrict__ Th_ns, const float* __restrict__ ws,
    float* __restrict__ out) {
  __shared__ float lout[64 * 35];
  const int t = blockIdx.x * 64 + threadIdx.x;
  float v[35];
#pragma unroll
  for (int m = 0; m < 35; ++m) v[m] = 0.f;
  if (t < TD) {
    const float* SYN = ws + WS_SYN;
    float dns[12][12];
#pragma unroll
    for (int i = 1; i < 12; ++i)
#pragma unroll
      for (int j = 0; j < i; ++j) dns[i][j] = Cden[i * 12 + j] * Wns_sub[j];
    float th[12];
#pragma unroll
    for (int i = 0; i < 12; ++i) th[i] = Th_ns[i];
    float ap[12], an[12];
#pragma unroll
    for (int i = 0; i < 12; ++i) { ap[i] = 0.f; an[i] = 0.f; }
    int start = t - 12; if (start < 0) start = 0;
    for (int tau = start; tau <= t; ++tau) {
      const float4* sr = (const float4*)(SYN + (size_t)tau * 24 + 12);
      float4 s0 = sr[0], s1 = sr[1], s2 = sr[2];
      float sn[12] = {s0.x, s0.y, s0.z, s0.w, s1.x, s1.y, s1.z, s1.w,
                      s2.x, s2.y, s2.z, s2.w};
#pragma unroll
      for (int i = 0; i < 12; ++i) {
        float x = sn[i] + th[i];
#pragma unroll
        for (int j = 0; j < i; ++j) x += dns[i][j] * ap[j];
        an[i] = sigf(x);
      }
      if (tau < t) {
#pragma unroll
        for (int i = 0; i < 12; ++i) ap[i] = an[i];
      }
    }
    float sns[12];
    {
      const float4* sr = (const float4*)(SYN + (size_t)t * 24);
      float4 s0 = sr[0], s1 = sr[1], s2 = sr[2];
      sns[0] = s0.x; sns[1] = s0.y; sns[2] = s0.z; sns[3] = s0.w;
      sns[4] = s1.x; sns[5] = s1.y; sns[6] = s1.z; sns[7] = s1.w;
      sns[8] = s2.x; sns[9] = s2.y; sns[10] = s2.z; sns[11] = s2.w;
    }
    float carry[12];
    carry[0] = (t > 0) ? Ws_sub[0] * sigf(SYN[(size_t)(t - 1) * 24] + Th_s[0]) : 0.f;
#pragma unroll
    for (int j = 1; j < 12; ++j) carry[j] = Ws_sub[j] * ap[j];
    float B[12];
#pragma unroll
    for (int i = 0; i < 12; ++i) {
      float x = sns[i] + Th_s[i];
#pragma unroll
      for (int j = 0; j < i; ++j) x += Cden[i * 12 + j] * carry[j];
      B[i] = sigf(x);
    }
    v[0] = B[0] * Ws_sub[0];
#pragma unroll
    for (int i = 1; i < 12; ++i) v[i] = an[i] * Ws_sub[i];
#pragma unroll
    for (int i = 0; i < 12; ++i) v[12 + i] = an[i] * Wns_sub[i];
#pragma unroll
    for (int i = 1; i < 12; ++i) v[23 + i] = B[i];
  }
#pragma unroll
  for (int m = 0; m < 35; ++m) lout[threadIdx.x * 35 + m] = v[m];
  __syncthreads();
  const int t0 = blockIdx.x * 64;
  int nrow = TD - t0; if (nrow > 64) nrow = 64;
  const int valid = nrow * 35;
  for (int p = threadIdx.x; p < valid; p += 64) out[(size_t)t0 * 35 + p] = lout[p];
}

extern "C" void kernel_launch(void* const* d_in, const int* in_sizes, int n_in,
                              void* d_out, int out_size, void* d_ws, size_t ws_size,
                              hipStream_t stream) {
  const float* Se = (const float*)d_in[0];
  const float* Si = (const float*)d_in[1];
  const float* Ce = (const float*)d_in[2];
  const float* Ci = (const float*)d_in[3];
  const float* Cden = (const float*)d_in[4];
  const float* Wsy_s = (const float*)d_in[5];
  const float* Wsy_ns = (const float*)d_in[6];
  const float* Del_s = (const float*)d_in[7];
  const float* Del_ns = (const float*)d_in[8];
  const float* Th_s = (const float*)d_in[9];
  const float* Th_ns = (const float*)d_in[10];
  const float* Ws_sub = (const float*)d_in[11];
  const float* Wns_sub = (const float*)d_in[12];
  // d_in[13..16] (hist/prop weights) multiply an identically-zero history buffer.
  float* ws = (float*)d_ws;
  float* out = (float*)d_out;

  k1_precomp<<<20, 256, 0, stream>>>(Ce, Ci, Wsy_s, Wsy_ns, Del_s, Del_ns, ws);
  k2_project<<<2048, 256, 0, stream>>>(Se, Si, ws);
  dim3 g3(313, 4);
  k3_conv<<<g3, 256, 0, stream>>>(ws);
  k45_out<<<313, 64, 0, stream>>>(Cden, Ws_sub, Wns_sub, Th_s, Th_ns, ws, out);
}

// Round 8
// 344.544 us; speedup vs baseline: 1.2713x; 1.2713x over previous
//
#include <hip/hip_runtime.h>

typedef unsigned int uint;
typedef unsigned long long u64;

#define TD 20000
// ws layout in float units:
//  H:   [200][12][4] = 9600 floats (FIR taps {e_s,i_s,e_ns,i_ns} per (k,s))
//  ME:  4 arrays x 512 u64  (E spread masks, element 4g+j -> array j idx g; pad 0)
//  MI:  4 arrays x 128 u64  (I spread masks, same split; pad 0)
//  IN:  [20000][24]  (e counts 0..11, i counts 12..23)
//  SYN: [20000][24]  (syn_s 0..11, syn_ns 12..23)
#define WS_H   0
#define WS_ME  9600
#define WS_MI  13696
#define WS_IN  14720
#define WS_SYN 494720

__device__ __forceinline__ float sigf(float x) { return 1.f / (1.f + __expf(-x)); }

// ---------------- K1: FIR kernels + split spread connectivity masks ----------------
__global__ __launch_bounds__(256) void k1_precomp(
    const float* __restrict__ Ce, const float* __restrict__ Ci,
    const float* __restrict__ Wsy_s, const float* __restrict__ Wsy_ns,
    const float* __restrict__ Del_s, const float* __restrict__ Del_ns,
    float* __restrict__ ws) {
  int p = blockIdx.x * 256 + threadIdx.x;
  if (p < 2400) {
    int k = p / 12, s = p - (p / 12) * 12;
    float o[4];
    for (int ch = 0; ch < 2; ++ch) {
      const float* W = ch ? Wsy_ns : Wsy_s;
      const float* D = ch ? Del_ns : Del_s;
      for (int c = 0; c < 2; ++c) {
        float ts = fmaxf((float)k - __expf(D[s * 2 + c]), 0.f);
        float v = 0.f;
        for (int b = 0; b < 3; ++b) {
          float tt = ts * __expf(-0.5f * (float)b);
          v += W[s * 6 + b * 2 + c] * tt * __expf(-tt);
        }
        o[ch * 2 + c] = v;
      }
    }
    float* H = ws + WS_H + (size_t)(k * 12 + s) * 4;
    H[0] = o[0]; H[1] = o[1]; H[2] = o[2]; H[3] = o[3];
  }
  int q = p - 2400;
  if (q >= 0 && q < 2500) {
    uint m = 0;
    if (q < 2000) {
      for (int s = 0; s < 12; ++s) m |= (Ce[s * 2000 + q] != 0.f ? (1u << s) : 0u);
    } else {
      int e = q - 2000;
      for (int s = 0; s < 12; ++s) m |= (Ci[s * 500 + e] != 0.f ? (1u << s) : 0u);
    }
    u64 sp = 0ull;
    for (int s = 0; s < 12; ++s) sp |= (u64)((m >> s) & 1u) << (5 * s);
    uint2 v = make_uint2((uint)sp, (uint)(sp >> 32));
    if (q < 2000) {
      int g = q >> 2, j = q & 3;
      ((uint2*)(ws + WS_ME))[j * 512 + g] = v;
    } else {
      int e = q - 2000;
      int g = e >> 2, j = e & 3;
      ((uint2*)(ws + WS_MI))[j * 128 + g] = v;
    }
  }
  // zero pads: E groups 500..511 (x4 arrays), I groups 125..127 (x4 arrays)
  int z = p - 4900;
  if (z >= 0 && z < 48) {
    int j = z / 12, g = 500 + z % 12;
    ((uint2*)(ws + WS_ME))[j * 512 + g] = make_uint2(0u, 0u);
  }
  int zi = p - 4948;
  if (zi >= 0 && zi < 12) {
    int j = zi / 3, g = 125 + zi % 3;
    ((uint2*)(ws + WS_MI))[j * 128 + g] = make_uint2(0u, 0u);
  }
}

// ---------------- K2: IN = S @ C^T via spread-mask accumulation ----------------
// v6 = v5 structure with the spill fixed: __launch_bounds__(256,4) gives a
// 128-VGPR budget (body needs ~80; round 6's (256,8) capped at 64 -> scratch
// spills -> 222 MB of HBM writes). 1024 persistent blocks (4/CU co-resident),
// masks preloaded once, waves grid-stride ~5 rows. Masks in 4 split u64
// arrays -> 8 B/lane LDS stride = free 2-way alias. Integer-exact.
__global__ __launch_bounds__(256, 4) void k2_project(
    const float* __restrict__ Se, const float* __restrict__ Si,
    float* __restrict__ ws) {
  __shared__ __align__(16) uint2 sp[2560];  // E: j*512+g (0..2047), I: 2048+j*128+g
  {
    const uint2* g = (const uint2*)(ws + WS_ME);
    for (int p = threadIdx.x; p < 2560; p += 256) sp[p] = g[p];
  }
  __syncthreads();
  const int lane = threadIdx.x & 63;
  const int wv = blockIdx.x * 4 + (threadIdx.x >> 6);  // 4096 waves
  float* INb = ws + WS_IN;
  const float4 z4 = make_float4(0.f, 0.f, 0.f, 0.f);

  for (int t = wv; t < TD; t += 4096) {
    const float4* Sr = (const float4*)(Se + (size_t)t * 2000);
    const float4* Sir = (const float4*)(Si + (size_t)t * 500);
    // ---- issue ALL global loads first ----
    float4 sv[8];
#pragma unroll
    for (int it = 0; it < 7; ++it) sv[it] = Sr[lane + it * 64];
    sv[7] = (lane < 52) ? Sr[448 + lane] : z4;       // i4 in [448,500)
    float4 si0 = Sir[lane];                          // i4 in [0,64)
    float4 si1 = (lane < 61) ? Sir[64 + lane] : z4;  // i4 in [64,125)

    // ---- E channel: flush 5-bit fields after 4 float4s (max 16 < 31) ----
    uint eTot[12];
#pragma unroll
    for (int s = 0; s < 12; ++s) eTot[s] = 0u;
    u64 acc = 0ull;
#pragma unroll
    for (int it = 0; it < 8; ++it) {
      int i4 = lane + it * 64;  // <= 511, pads are zero
      uint2 a0 = sp[i4];
      uint2 a1 = sp[512 + i4];
      uint2 a2 = sp[1024 + i4];
      uint2 a3 = sp[1536 + i4];
      acc += (sv[it].x != 0.f ? ((u64)a0.x | ((u64)a0.y << 32)) : 0ull);
      acc += (sv[it].y != 0.f ? ((u64)a1.x | ((u64)a1.y << 32)) : 0ull);
      acc += (sv[it].z != 0.f ? ((u64)a2.x | ((u64)a2.y << 32)) : 0ull);
      acc += (sv[it].w != 0.f ? ((u64)a3.x | ((u64)a3.y << 32)) : 0ull);
      if (it == 3) {
#pragma unroll
        for (int s = 0; s < 12; ++s) eTot[s] += (uint)(acc >> (5 * s)) & 31u;
        acc = 0ull;
      }
    }
#pragma unroll
    for (int s = 0; s < 12; ++s) eTot[s] += (uint)(acc >> (5 * s)) & 31u;

    // ---- I channel (max 8 adds/field, no flush) ----
    u64 accI = 0ull;
    {
      int i4 = lane;
      uint2 a0 = sp[2048 + i4];
      uint2 a1 = sp[2176 + i4];
      uint2 a2 = sp[2304 + i4];
      uint2 a3 = sp[2432 + i4];
      accI += (si0.x != 0.f ? ((u64)a0.x | ((u64)a0.y << 32)) : 0ull);
      accI += (si0.y != 0.f ? ((u64)a1.x | ((u64)a1.y << 32)) : 0ull);
      accI += (si0.z != 0.f ? ((u64)a2.x | ((u64)a2.y << 32)) : 0ull);
      accI += (si0.w != 0.f ? ((u64)a3.x | ((u64)a3.y << 32)) : 0ull);
      i4 = 64 + lane;  // <= 127, pads zero
      uint2 b0 = sp[2048 + i4];
      uint2 b1 = sp[2176 + i4];
      uint2 b2 = sp[2304 + i4];
      uint2 b3 = sp[2432 + i4];
      accI += (si1.x != 0.f ? ((u64)b0.x | ((u64)b0.y << 32)) : 0ull);
      accI += (si1.y != 0.f ? ((u64)b1.x | ((u64)b1.y << 32)) : 0ull);
      accI += (si1.z != 0.f ? ((u64)b2.x | ((u64)b2.y << 32)) : 0ull);
      accI += (si1.w != 0.f ? ((u64)b3.x | ((u64)b3.y << 32)) : 0ull);
    }

    uint pk[12];
#pragma unroll
    for (int s = 0; s < 12; ++s)
      pk[s] = eTot[s] | (((uint)(accI >> (5 * s)) & 31u) << 16);
#pragma unroll
    for (int s = 0; s < 12; ++s) {
      uint v = pk[s];
      v += __shfl_xor(v, 32, 64);
      v += __shfl_xor(v, 16, 64);
      v += __shfl_xor(v, 8, 64);
      v += __shfl_xor(v, 4, 64);
      v += __shfl_xor(v, 2, 64);
      v += __shfl_xor(v, 1, 64);
      pk[s] = v;
    }
    if (lane == 0) {
      float4* o = (float4*)(INb + (size_t)t * 24);
      o[0] = make_float4((float)(pk[0] & 0xffffu), (float)(pk[1] & 0xffffu),
                         (float)(pk[2] & 0xffffu), (float)(pk[3] & 0xffffu));
      o[1] = make_float4((float)(pk[4] & 0xffffu), (float)(pk[5] & 0xffffu),
                         (float)(pk[6] & 0xffffu), (float)(pk[7] & 0xffffu));
      o[2] = make_float4((float)(pk[8] & 0xffffu), (float)(pk[9] & 0xffffu),
                         (float)(pk[10] & 0xffffu), (float)(pk[11] & 0xffffu));
      o[3] = make_float4((float)(pk[0] >> 16), (float)(pk[1] >> 16),
                         (float)(pk[2] >> 16), (float)(pk[3] >> 16));
      o[4] = make_float4((float)(pk[4] >> 16), (float)(pk[5] >> 16),
                         (float)(pk[6] >> 16), (float)(pk[7] >> 16));
      o[5] = make_float4((float)(pk[8] >> 16), (float)(pk[9] >> 16),
                         (float)(pk[10] >> 16), (float)(pk[11] >> 16));
    }
  }
}

// ---------------- K3: causal FIR, K=200, s-group split across blockIdx.y ----------------
__global__ __launch_bounds__(256) void k3_conv(float* __restrict__ ws) {
  __shared__ float tile[6 * 264];
  __shared__ float red[4 * 64 * 7];
  const int g = blockIdx.y;        // subunit group: s in [3g, 3g+3)
  const int t0 = blockIdx.x * 64;
  const float* INb = ws + WS_IN;
  for (int p = threadIdx.x; p < 263 * 6; p += 256) {
    int row = p / 6, c = p - row * 6;
    int ch = (c < 3) ? (3 * g + c) : (9 + 3 * g + c);
    int gt = t0 - 199 + row;
    tile[c * 264 + row] = (gt >= 0 && gt < TD) ? INb[(size_t)gt * 24 + ch] : 0.f;
  }
  __syncthreads();
  const int lane = threadIdx.x & 63;
  const int q = threadIdx.x >> 6;
  const float4* H4 = (const float4*)(ws + WS_H);
  float accs[3] = {0.f, 0.f, 0.f}, accn[3] = {0.f, 0.f, 0.f};
  for (int kk = 0; kk < 25; ++kk) {
    int k = q * 50 + kk * 2;
    int rb = lane + 198 - k;
#pragma unroll
    for (int s = 0; s < 3; ++s) {
      float ve0 = tile[s * 264 + rb];
      float ve1 = tile[s * 264 + rb + 1];
      float vi0 = tile[(3 + s) * 264 + rb];
      float vi1 = tile[(3 + s) * 264 + rb + 1];
      float4 h0 = H4[k * 12 + 3 * g + s];
      float4 h1 = H4[(k + 1) * 12 + 3 * g + s];
      accs[s] += h0.x * ve1 + h0.y * vi1 + h1.x * ve0 + h1.y * vi0;
      accn[s] += h0.z * ve1 + h0.w * vi1 + h1.z * ve0 + h1.w * vi0;
    }
  }
  float* mr = red + (q * 64 + lane) * 7;
#pragma unroll
  for (int s = 0; s < 3; ++s) { mr[s] = accs[s]; mr[3 + s] = accn[s]; }
  __syncthreads();
  for (int p = threadIdx.x; p < 64 * 6; p += 256) {
    int row = p / 6, c = p - row * 6;
    if (t0 + row < TD) {
      float sum = red[row * 7 + c] + red[(64 + row) * 7 + c] +
                  red[(128 + row) * 7 + c] + red[(192 + row) * 7 + c];
      int ch = (c < 3) ? (3 * g + c) : (9 + 3 * g + c);
      ws[WS_SYN + (size_t)(t0 + row) * 24 + ch] = sum;
    }
  }
}

// ---------------- K45: one thread per t; nilpotent C_den => 13-step warm-up
// makes A[t-1], A[t] exact; s-chain closed-form given A[t-1]. ----------------
__global__ void k45_out(
    const float* __restrict__ Cden, const float* __restrict__ Ws_sub,
    const float* __restrict__ Wns_sub, const float* __restrict__ Th_s,
    const float* __restrict__ Th_ns, const float* __restrict__ ws,
    float* __restrict__ out) {
  __shared__ float lout[64 * 35];
  const int t = blockIdx.x * 64 + threadIdx.x;
  float v[35];
#pragma unroll
  for (int m = 0; m < 35; ++m) v[m] = 0.f;
  if (t < TD) {
    const float* SYN = ws + WS_SYN;
    float dns[12][12];
#pragma unroll
    for (int i = 1; i < 12; ++i)
#pragma unroll
      for (int j = 0; j < i; ++j) dns[i][j] = Cden[i * 12 + j] * Wns_sub[j];
    float th[12];
#pragma unroll
    for (int i = 0; i < 12; ++i) th[i] = Th_ns[i];
    float ap[12], an[12];
#pragma unroll
    for (int i = 0; i < 12; ++i) { ap[i] = 0.f; an[i] = 0.f; }
    int start = t - 12; if (start < 0) start = 0;
    for (int tau = start; tau <= t; ++tau) {
      const float4* sr = (const float4*)(SYN + (size_t)tau * 24 + 12);
      float4 s0 = sr[0], s1 = sr[1], s2 = sr[2];
      float sn[12] = {s0.x, s0.y, s0.z, s0.w, s1.x, s1.y, s1.z, s1.w,
                      s2.x, s2.y, s2.z, s2.w};
#pragma unroll
      for (int i = 0; i < 12; ++i) {
        float x = sn[i] + th[i];
#pragma unroll
        for (int j = 0; j < i; ++j) x += dns[i][j] * ap[j];
        an[i] = sigf(x);
      }
      if (tau < t) {
#pragma unroll
        for (int i = 0; i < 12; ++i) ap[i] = an[i];
      }
    }
    float sns[12];
    {
      const float4* sr = (const float4*)(SYN + (size_t)t * 24);
      float4 s0 = sr[0], s1 = sr[1], s2 = sr[2];
      sns[0] = s0.x; sns[1] = s0.y; sns[2] = s0.z; sns[3] = s0.w;
      sns[4] = s1.x; sns[5] = s1.y; sns[6] = s1.z; sns[7] = s1.w;
      sns[8] = s2.x; sns[9] = s2.y; sns[10] = s2.z; sns[11] = s2.w;
    }
    float carry[12];
    carry[0] = (t > 0) ? Ws_sub[0] * sigf(SYN[(size_t)(t - 1) * 24] + Th_s[0]) : 0.f;
#pragma unroll
    for (int j = 1; j < 12; ++j) carry[j] = Ws_sub[j] * ap[j];
    float B[12];
#pragma unroll
    for (int i = 0; i < 12; ++i) {
      float x = sns[i] + Th_s[i];
#pragma unroll
      for (int j = 0; j < i; ++j) x += Cden[i * 12 + j] * carry[j];
      B[i] = sigf(x);
    }
    v[0] = B[0] * Ws_sub[0];
#pragma unroll
    for (int i = 1; i < 12; ++i) v[i] = an[i] * Ws_sub[i];
#pragma unroll
    for (int i = 0; i < 12; ++i) v[12 + i] = an[i] * Wns_sub[i];
#pragma unroll
    for (int i = 1; i < 12; ++i) v[23 + i] = B[i];
  }
#pragma unroll
  for (int m = 0; m < 35; ++m) lout[threadIdx.x * 35 + m] = v[m];
  __syncthreads();
  const int t0 = blockIdx.x * 64;
  int nrow = TD - t0; if (nrow > 64) nrow = 64;
  const int valid = nrow * 35;
  for (int p = threadIdx.x; p < valid; p += 64) out[(size_t)t0 * 35 + p] = lout[p];
}

extern "C" void kernel_launch(void* const* d_in, const int* in_sizes, int n_in,
                              void* d_out, int out_size, void* d_ws, size_t ws_size,
                              hipStream_t stream) {
  const float* Se = (const float*)d_in[0];
  const float* Si = (const float*)d_in[1];
  const float* Ce = (const float*)d_in[2];
  const float* Ci = (const float*)d_in[3];
  const float* Cden = (const float*)d_in[4];
  const float* Wsy_s = (const float*)d_in[5];
  const float* Wsy_ns = (const float*)d_in[6];
  const float* Del_s = (const float*)d_in[7];
  const float* Del_ns = (const float*)d_in[8];
  const float* Th_s = (const float*)d_in[9];
  const float* Th_ns = (const float*)d_in[10];
  const float* Ws_sub = (const float*)d_in[11];
  const float* Wns_sub = (const float*)d_in[12];
  // d_in[13..16] (hist/prop weights) multiply an identically-zero history buffer.
  float* ws = (float*)d_ws;
  float* out = (float*)d_out;

  k1_precomp<<<20, 256, 0, stream>>>(Ce, Ci, Wsy_s, Wsy_ns, Del_s, Del_ns, ws);
  k2_project<<<1024, 256, 0, stream>>>(Se, Si, ws);
  dim3 g3(313, 4);
  k3_conv<<<g3, 256, 0, stream>>>(ws);
  k45_out<<<313, 64, 0, stream>>>(Cden, Ws_sub, Wns_sub, Th_s, Th_ns, ws, out);
}